// Round 20
// baseline (123.503 us; speedup 1.0000x reference)
//
#include <hip/hip_runtime.h>

#define NB 2
#define NS 2048
#define NDM 1024
#define NH 16
#define NDK 64

typedef unsigned int u32;
typedef u32 u32x4 __attribute__((ext_vector_type(4)));
typedef float f32x4 __attribute__((ext_vector_type(4)));
typedef float f32x2 __attribute__((ext_vector_type(2)));
typedef __bf16 bf16x8 __attribute__((ext_vector_type(8)));
typedef __bf16 bf16x4 __attribute__((ext_vector_type(4)));
typedef __bf16 bf16x2 __attribute__((ext_vector_type(2)));

#define QSCALE 0.18033688011112042f   // 0.125 * log2(e): exp2-domain softmax
#define EXP2F(x) __builtin_amdgcn_exp2f(x)   // raw v_exp_f32

__device__ __forceinline__ void gload_lds16(const __bf16* g, __bf16* l) {
    __builtin_amdgcn_global_load_lds(
        (const __attribute__((address_space(1))) unsigned int*)(g),
        (__attribute__((address_space(3))) unsigned int*)(l), 16, 0, 0);
}

// ---------------- casts + RoPE table in ONE launch ----------------
// Q/K weight ROWS permuted while casting: within head h, feature fr -> position
// pr = (fr>>1) | ((fr&1)<<5), so RoPE pairs land in-lane after the GEMM.
__global__ __launch_bounds__(256) void cvt_all(const float* __restrict__ x,
                                               const float* __restrict__ qw,
                                               const float* __restrict__ kw,
                                               const float* __restrict__ vw,
                                               const float* __restrict__ ow,
                                               const int* __restrict__ tp,
                                               __bf16* __restrict__ xb,
                                               __bf16* __restrict__ wqkv,
                                               __bf16* __restrict__ owb,
                                               float* __restrict__ tbl) {
    const int i = blockIdx.x * 256 + threadIdx.x;   // grid 8448
    if (i >= 2097152) {
        const int it = i - 2097152;                  // 0..65535 = NS*32
        if (it < NS * 32) {
            const int s = it >> 5, jj = it & 31;
            const float pos = (float)tp[s];
            const float inv = exp2f(-0.41524101186092f * (float)jj);  // 10000^(-jj/32)
            const float ang = pos * inv;
            float sn, cs;
            sincosf(ang, &sn, &cs);
            f32x2 o; o[0] = cs; o[1] = sn;
            *(f32x2*)&tbl[(size_t)it * 2] = o;
        }
        return;
    }
    const float* src;
    __bf16* dst;
    if (i < 1048576) {
        src = x + (size_t)i * 4;
        dst = xb + (size_t)i * 4;
    } else {
        const int j = i - 1048576;
        const int seg = j >> 18;            // 262144 float4 per weight
        const int off = j & 0x3FFFF;
        src = ((seg == 0) ? qw : (seg == 1) ? kw : (seg == 2) ? vw : ow) + (size_t)off * 4;
        if (seg <= 1) {
            const int row = off >> 8;       // 256 float4 per 1024-elem row
            const int c4 = off & 255;
            const int h = row >> 6, fr = row & 63;
            const int pr = (fr >> 1) | ((fr & 1) << 5);
            dst = wqkv + (((size_t)(seg << 10) + h * 64 + pr) << 10) + (size_t)c4 * 4;
        } else {
            dst = ((seg == 3) ? owb : wqkv + (size_t)seg * 1048576) + (size_t)off * 4;
        }
    }
    f32x4 v = *(const f32x4*)src;
    bf16x4 o;
    o[0] = (__bf16)v[0]; o[1] = (__bf16)v[1]; o[2] = (__bf16)v[2]; o[3] = (__bf16)v[3];
    *(bf16x4*)dst = o;
}

// ---------------- QKV GEMM 128x128, TRIPLE-buffered staging (2 tiles in flight) ----------
// Fused RoPE epilogue (in-lane pairs). Ledger: prologue stages T0,T1 (16 outstanding);
// iter i: vmcnt(8) retires T_i, barrier, stage T_{i+2} into buffer (i+2)%3 (freed by
// iter i-1's end barrier), compute, lgkm(0)+barrier.
__global__ __launch_bounds__(256) void gemm_qkv128(const __bf16* __restrict__ A,
                                                   const __bf16* __restrict__ Bt,
                                                   const float* __restrict__ tbl,
                                                   __bf16* __restrict__ Qr,
                                                   __bf16* __restrict__ Kr,
                                                   __bf16* __restrict__ Vt) {
    __shared__ __bf16 As[3][128 * 64];
    __shared__ __bf16 Bs[3][128 * 64];
    const int K = 1024, lda = 1024, ldb = 1024;
    const int tid = threadIdx.x;
    const int lane = tid & 63, w = tid >> 6;
    const int wr = w >> 1, wc = w & 1;
    const int l15 = lane & 15, lg = lane >> 4;
    const int m0 = blockIdx.y * 128, n0 = blockIdx.x * 128;
    const int crow = lane >> 3;
    const int csw = ((lane & 7) ^ crow) * 8;

    f32x4 acc[4][4];
    const f32x4 z = {0.f, 0.f, 0.f, 0.f};
#pragma unroll
    for (int i = 0; i < 4; ++i)
#pragma unroll
        for (int jx = 0; jx < 4; ++jx) acc[i][jx] = z;

    auto stage = [&](int buf, int k0) {
#pragma unroll
        for (int ch = 0; ch < 4; ++ch) {
            const int cid = w * 4 + ch;
            const int ra = cid * 8 + crow;
            gload_lds16(&A[(size_t)(m0 + ra) * lda + k0 + csw], &As[buf][cid * 512]);
            gload_lds16(&Bt[(size_t)(n0 + ra) * ldb + k0 + csw], &Bs[buf][cid * 512]);
        }
    };

    stage(0, 0);
    stage(1, 64);
    for (int k0 = 0; k0 < K; k0 += 64) {
        const int cur = (k0 >> 6) % 3;
        if (k0 + 64 < K) {
            asm volatile("s_waitcnt vmcnt(8)" ::: "memory");   // cur's 8 landed
        } else {
            asm volatile("s_waitcnt vmcnt(0)" ::: "memory");
        }
        __builtin_amdgcn_s_barrier();
        __builtin_amdgcn_sched_barrier(0);
        if (k0 + 128 < K) stage((cur + 2) % 3, k0 + 128);      // 2 tiles ahead
#pragma unroll
        for (int kc = 0; kc < 2; ++kc) {
            bf16x8 af[4], bfv[4];
#pragma unroll
            for (int i = 0; i < 4; ++i) {
                const int ra = wr * 64 + i * 16 + l15;
                const int rb = wc * 64 + i * 16 + l15;
                af[i]  = *(const bf16x8*)&As[cur][ra * 64 + ((kc * 32 + lg * 8) ^ ((ra & 7) << 3))];
                bfv[i] = *(const bf16x8*)&Bs[cur][rb * 64 + ((kc * 32 + lg * 8) ^ ((rb & 7) << 3))];
            }
#pragma unroll
            for (int sm = 0; sm < 4; ++sm)
#pragma unroll
                for (int sn = 0; sn < 4; ++sn)
                    acc[sm][sn] = __builtin_amdgcn_mfma_f32_16x16x32_bf16(af[sm], bfv[sn], acc[sm][sn], 0, 0, 0);
        }
        asm volatile("s_waitcnt lgkmcnt(0)" ::: "memory");
        __builtin_amdgcn_s_barrier();
        __builtin_amdgcn_sched_barrier(0);
    }
    if (n0 < 2048) {
        __bf16* dst = (n0 < 1024) ? Qr : Kr;
        const float scale = (n0 < 1024) ? QSCALE : 1.0f;
        const int h = ((n0 & 1023) + wc * 64) >> 6;
#pragma unroll
        for (int sm = 0; sm < 4; ++sm)
#pragma unroll
            for (int j = 0; j < 4; ++j) {
                const int row = m0 + wr * 64 + sm * 16 + lg * 4 + j;
                const int b = row >> 11, s = row & (NS - 1);
                const size_t base = ((size_t)(b * NH + h) * NS + s) * 64;
#pragma unroll
                for (int pp = 0; pp < 2; ++pp) {
                    const int jj = pp * 16 + l15;
                    f32x2 cssn = *(const f32x2*)&tbl[((size_t)s * 32 + jj) * 2];
                    const float e  = acc[sm][pp][j];
                    const float od = acc[sm][pp + 2][j];
                    bf16x2 ov;
                    ov[0] = (__bf16)((e * cssn[0] - od * cssn[1]) * scale);
                    ov[1] = (__bf16)((e * cssn[1] + od * cssn[0]) * scale);
                    *(bf16x2*)&dst[base + 2 * jj] = ov;
                }
            }
    } else {
#pragma unroll
        for (int sm = 0; sm < 4; ++sm)
#pragma unroll
            for (int sn = 0; sn < 4; ++sn) {
                const int col = (n0 - 2048) + wc * 64 + sn * 16 + l15;
                const int h = col >> 6, d = col & 63;
                const int row = m0 + wr * 64 + sm * 16 + lg * 4;
                const int b = row >> 11, s = row & (NS - 1);
                bf16x4 ov;
#pragma unroll
                for (int j = 0; j < 4; ++j) ov[j] = (__bf16)acc[sm][sn][j];
                *(bf16x4*)&Vt[((size_t)(b * NH + h) * 64 + d) * NS + s] = ov;
            }
    }
}

// ---------------- GEMM 128x128, triple-buffered (output projection) ----------------
template <typename TOUT>
__global__ __launch_bounds__(256) void gemm_bt128(const __bf16* __restrict__ A,
                                                  const __bf16* __restrict__ Bt,
                                                  TOUT* __restrict__ C,
                                                  int K, int lda, int ldb, int ldc) {
    __shared__ __bf16 As[3][128 * 64];
    __shared__ __bf16 Bs[3][128 * 64];
    const int tid = threadIdx.x;
    const int lane = tid & 63, w = tid >> 6;
    const int wr = w >> 1, wc = w & 1;
    const int l15 = lane & 15, lg = lane >> 4;
    const int m0 = blockIdx.y * 128, n0 = blockIdx.x * 128;
    const int crow = lane >> 3;
    const int csw = ((lane & 7) ^ crow) * 8;

    f32x4 acc[4][4];
    const f32x4 z = {0.f, 0.f, 0.f, 0.f};
#pragma unroll
    for (int i = 0; i < 4; ++i)
#pragma unroll
        for (int jx = 0; jx < 4; ++jx) acc[i][jx] = z;

    auto stage = [&](int buf, int k0) {
#pragma unroll
        for (int ch = 0; ch < 4; ++ch) {
            const int cid = w * 4 + ch;
            const int ra = cid * 8 + crow;
            gload_lds16(&A[(size_t)(m0 + ra) * lda + k0 + csw], &As[buf][cid * 512]);
            gload_lds16(&Bt[(size_t)(n0 + ra) * ldb + k0 + csw], &Bs[buf][cid * 512]);
        }
    };

    stage(0, 0);
    stage(1, 64);
    for (int k0 = 0; k0 < K; k0 += 64) {
        const int cur = (k0 >> 6) % 3;
        if (k0 + 64 < K) {
            asm volatile("s_waitcnt vmcnt(8)" ::: "memory");
        } else {
            asm volatile("s_waitcnt vmcnt(0)" ::: "memory");
        }
        __builtin_amdgcn_s_barrier();
        __builtin_amdgcn_sched_barrier(0);
        if (k0 + 128 < K) stage((cur + 2) % 3, k0 + 128);
#pragma unroll
        for (int kc = 0; kc < 2; ++kc) {
            bf16x8 af[4], bfv[4];
#pragma unroll
            for (int i = 0; i < 4; ++i) {
                const int ra = wr * 64 + i * 16 + l15;
                const int rb = wc * 64 + i * 16 + l15;
                af[i]  = *(const bf16x8*)&As[cur][ra * 64 + ((kc * 32 + lg * 8) ^ ((ra & 7) << 3))];
                bfv[i] = *(const bf16x8*)&Bs[cur][rb * 64 + ((kc * 32 + lg * 8) ^ ((rb & 7) << 3))];
            }
#pragma unroll
            for (int sm = 0; sm < 4; ++sm)
#pragma unroll
                for (int sn = 0; sn < 4; ++sn)
                    acc[sm][sn] = __builtin_amdgcn_mfma_f32_16x16x32_bf16(af[sm], bfv[sn], acc[sm][sn], 0, 0, 0);
        }
        asm volatile("s_waitcnt lgkmcnt(0)" ::: "memory");
        __builtin_amdgcn_s_barrier();
        __builtin_amdgcn_sched_barrier(0);
    }
#pragma unroll
    for (int sm = 0; sm < 4; ++sm)
#pragma unroll
        for (int sn = 0; sn < 4; ++sn)
#pragma unroll
            for (int j = 0; j < 4; ++j) {
                const int row = m0 + wr * 64 + sm * 16 + lg * 4 + j;
                const int col = n0 + wc * 64 + sn * 16 + l15;
                C[(size_t)row * ldc + col] = (TOUT)acc[sm][sn][j];
            }
}

// K staging permutation (zero-exchange PV): LDS slot rt holds K row kperm(rt).
__device__ __forceinline__ int kperm(int rt) {
    const int ct = rt >> 4, rr = rt & 15;
    return ((rr >> 2) << 3) + ((ct >> 1) << 5) + ((ct & 1) << 2) + (rr & 3);
}

// ---------------- causal flash attention v9: 1 q-tile (64 rows) per block, grid 1024 ----
__global__ __launch_bounds__(256) void attn9(const __bf16* __restrict__ Qr,
                                             const __bf16* __restrict__ Kr,
                                             const __bf16* __restrict__ Vt,
                                             __bf16* __restrict__ O) {
    const int lid = blockIdx.x;
    const int xcd = lid & 7;
    const int g = lid >> 3;                 // 0..127
    const int bh = xcd * 4 + (g & 3);       // 4 heads per XCD (L2 locality)
    const int ti = 31 - (g >> 2);           // 31..0  -> longest blocks dispatch first
    const int q0 = ti * 64;
    const int b = bh >> 4, h = bh & 15;
    const int tid = threadIdx.x;
    const int w = tid >> 6, lane = tid & 63;
    const int l15 = lane & 15, lg = lane >> 4;
    const __bf16* Qb = Qr + (size_t)bh * NS * 64;
    const __bf16* Kb = Kr + (size_t)bh * NS * 64;
    const __bf16* Vb = Vt + (size_t)bh * 64 * NS;

    __shared__ __bf16 Ks[2][64 * 64];
    __shared__ __bf16 Vs[2][64 * 64];

    const int rb = q0 + w * 16;

    bf16x8 qf[2];
#pragma unroll
    for (int kc = 0; kc < 2; ++kc)
        qf[kc] = *(const bf16x8*)(Qb + (size_t)(rb + l15) * 64 + kc * 32 + lg * 8);

    f32x4 oacc[4];
    const f32x4 z = {0.f, 0.f, 0.f, 0.f};
#pragma unroll
    for (int ct = 0; ct < 4; ++ct) oacc[ct] = z;
    float lsum = 0.f;

    const int crow = lane >> 3;
    const int cswz = ((lane & 7) ^ crow) * 8;

#pragma unroll
    for (int pp = 0; pp < 2; ++pp) {
        const int ch = w + pp * 4;
        const int rt = ch * 8 + crow;
        gload_lds16(Kb + (size_t)kperm(rt) * 64 + cswz, &Ks[0][ch * 512]);
        gload_lds16(Vb + (size_t)rt * NS + 0 + cswz, &Vs[0][ch * 512]);
    }
    __syncthreads();

    const int nt = ti + 1;
    for (int t = 0; t < nt; ++t) {
        const int cur = t & 1;
        const int kv0 = t << 6;
        if (t + 1 < nt) {
            const int kv1 = kv0 + 64;
#pragma unroll
            for (int pp = 0; pp < 2; ++pp) {
                const int ch = w + pp * 4;
                const int rt = ch * 8 + crow;
                gload_lds16(Kb + (size_t)(kv1 + kperm(rt)) * 64 + cswz, &Ks[cur ^ 1][ch * 512]);
                gload_lds16(Vb + (size_t)rt * NS + kv1 + cswz, &Vs[cur ^ 1][ch * 512]);
            }
        }
        f32x4 sc[4];
#pragma unroll
        for (int ct = 0; ct < 4; ++ct) sc[ct] = z;
#pragma unroll
        for (int kc = 0; kc < 2; ++kc) {
            bf16x8 kf[4];
#pragma unroll
            for (int ct = 0; ct < 4; ++ct) {
                const int rt = ct * 16 + l15;
                kf[ct] = *(const bf16x8*)&Ks[cur][rt * 64 + ((kc * 32 + lg * 8) ^ ((rt & 7) << 3))];
            }
#pragma unroll
            for (int ct = 0; ct < 4; ++ct)
                sc[ct] = __builtin_amdgcn_mfma_f32_16x16x32_bf16(kf[ct], qf[kc], sc[ct], 0, 0, 0);
        }
        const int qrow = rb + l15;
        if (t == nt - 1) {
#pragma unroll
            for (int ct = 0; ct < 4; ++ct)
#pragma unroll
                for (int j = 0; j < 4; ++j) {
                    const int kvg = kv0 + ((ct >> 1) << 5) + lg * 8 + ((ct & 1) << 2) + j;
                    if (kvg > qrow) sc[ct][j] = -1e30f;
                }
        }
        float ps = 0.f;
#pragma unroll
        for (int ct = 0; ct < 4; ++ct)
#pragma unroll
            for (int j = 0; j < 4; ++j) {
                const float e = EXP2F(sc[ct][j]);
                sc[ct][j] = e;
                ps += e;
            }
        lsum += ps;
        bf16x8 pb[2];
#pragma unroll
        for (int kc = 0; kc < 2; ++kc) {
            bf16x8 pk;
            pk[0] = (__bf16)sc[2 * kc][0];     pk[1] = (__bf16)sc[2 * kc][1];
            pk[2] = (__bf16)sc[2 * kc][2];     pk[3] = (__bf16)sc[2 * kc][3];
            pk[4] = (__bf16)sc[2 * kc + 1][0]; pk[5] = (__bf16)sc[2 * kc + 1][1];
            pk[6] = (__bf16)sc[2 * kc + 1][2]; pk[7] = (__bf16)sc[2 * kc + 1][3];
            pb[kc] = pk;
        }
#pragma unroll
        for (int kc = 0; kc < 2; ++kc) {
            bf16x8 vf[4];
#pragma unroll
            for (int ct = 0; ct < 4; ++ct) {
                const int rt = ct * 16 + l15;
                vf[ct] = *(const bf16x8*)&Vs[cur][rt * 64 + ((kc * 32 + lg * 8) ^ ((rt & 7) << 3))];
            }
#pragma unroll
            for (int ct = 0; ct < 4; ++ct)
                oacc[ct] = __builtin_amdgcn_mfma_f32_16x16x32_bf16(vf[ct], pb[kc], oacc[ct], 0, 0, 0);
        }
        __syncthreads();
    }
    float tot = lsum;
    tot += __shfl_xor(tot, 16, 64);
    tot += __shfl_xor(tot, 32, 64);
    const float rl = 1.0f / tot;
    const size_t rowoff = (size_t)(b * NS + rb + l15) * NDM + h * 64 + lg * 4;
#pragma unroll
    for (int ct = 0; ct < 4; ++ct) {
        bf16x4 ov;
#pragma unroll
        for (int j = 0; j < 4; ++j) ov[j] = (__bf16)(oacc[ct][j] * rl);
        *(bf16x4*)&O[rowoff + ct * 16] = ov;
    }
}

// ---------------- launch ----------------
extern "C" void kernel_launch(void* const* d_in, const int* in_sizes, int n_in,
                              void* d_out, int out_size, void* d_ws, size_t ws_size,
                              hipStream_t stream) {
    const float* x  = (const float*)d_in[0];
    const float* Qw = (const float*)d_in[1];
    const float* Kw = (const float*)d_in[2];
    const float* Vw = (const float*)d_in[3];
    const float* Ow = (const float*)d_in[4];
    const int*   tp = (const int*)d_in[5];
    float* out = (float*)d_out;

    char* ws = (char*)d_ws;
    size_t off = 0;
    auto alloc = [&](size_t bytes) -> void* {
        void* p = ws + off;
        off += (bytes + 255) & ~(size_t)255;
        return p;
    };
    __bf16* xb   = (__bf16*)alloc((size_t)4096 * 1024 * 2);
    __bf16* wqkv = (__bf16*)alloc((size_t)3072 * 1024 * 2);
    __bf16* owb  = (__bf16*)alloc((size_t)1024 * 1024 * 2);
    __bf16* qr   = (__bf16*)alloc((size_t)32 * 2048 * 64 * 2);
    __bf16* kr   = (__bf16*)alloc((size_t)32 * 2048 * 64 * 2);
    __bf16* vt   = (__bf16*)alloc((size_t)32 * 64 * 2048 * 2);
    __bf16* ob   = (__bf16*)alloc((size_t)4096 * 1024 * 2);
    float*  tbl  = (float*)alloc((size_t)NS * 32 * 2 * 4);

    cvt_all<<<8448, 256, 0, stream>>>(x, Qw, Kw, Vw, Ow, tp, xb, wqkv, owb, tbl);

    gemm_qkv128<<<dim3(3072 / 128, 4096 / 128), 256, 0, stream>>>(xb, wqkv, tbl, qr, kr, vt);
    attn9<<<dim3(1024), 256, 0, stream>>>(qr, kr, vt, ob);
    gemm_bt128<float><<<dim3(1024 / 128, 4096 / 128), 256, 0, stream>>>(
        ob, owb, out, 1024, 1024, 1024, 1024);
}

// Round 21
// 108.847 us; speedup vs baseline: 1.1346x; 1.1346x over previous
//
#include <hip/hip_runtime.h>

#define NB 2
#define NS 2048
#define NDM 1024
#define NH 16
#define NDK 64

typedef unsigned int u32;
typedef u32 u32x4 __attribute__((ext_vector_type(4)));
typedef float f32x4 __attribute__((ext_vector_type(4)));
typedef float f32x2 __attribute__((ext_vector_type(2)));
typedef __bf16 bf16x8 __attribute__((ext_vector_type(8)));
typedef __bf16 bf16x4 __attribute__((ext_vector_type(4)));
typedef __bf16 bf16x2 __attribute__((ext_vector_type(2)));

#define QSCALE 0.18033688011112042f   // 0.125 * log2(e): exp2-domain softmax
#define EXP2F(x) __builtin_amdgcn_exp2f(x)   // raw v_exp_f32

__device__ __forceinline__ void gload_lds16(const __bf16* g, __bf16* l) {
    __builtin_amdgcn_global_load_lds(
        (const __attribute__((address_space(1))) unsigned int*)(g),
        (__attribute__((address_space(3))) unsigned int*)(l), 16, 0, 0);
}

// ---------------- casts + RoPE table in ONE launch ----------------
// Q/K weight ROWS permuted while casting: within head h, feature fr -> position
// pr = (fr>>1) | ((fr&1)<<5), so RoPE pairs land in-lane after the GEMM.
__global__ __launch_bounds__(256) void cvt_all(const float* __restrict__ x,
                                               const float* __restrict__ qw,
                                               const float* __restrict__ kw,
                                               const float* __restrict__ vw,
                                               const float* __restrict__ ow,
                                               const int* __restrict__ tp,
                                               __bf16* __restrict__ xb,
                                               __bf16* __restrict__ wqkv,
                                               __bf16* __restrict__ owb,
                                               float* __restrict__ tbl) {
    const int i = blockIdx.x * 256 + threadIdx.x;   // grid 8448
    if (i >= 2097152) {
        const int it = i - 2097152;                  // 0..65535 = NS*32
        if (it < NS * 32) {
            const int s = it >> 5, jj = it & 31;
            const float pos = (float)tp[s];
            const float inv = exp2f(-0.41524101186092f * (float)jj);  // 10000^(-jj/32)
            const float ang = pos * inv;
            float sn, cs;
            sincosf(ang, &sn, &cs);
            f32x2 o; o[0] = cs; o[1] = sn;
            *(f32x2*)&tbl[(size_t)it * 2] = o;
        }
        return;
    }
    const float* src;
    __bf16* dst;
    if (i < 1048576) {
        src = x + (size_t)i * 4;
        dst = xb + (size_t)i * 4;
    } else {
        const int j = i - 1048576;
        const int seg = j >> 18;            // 262144 float4 per weight
        const int off = j & 0x3FFFF;
        src = ((seg == 0) ? qw : (seg == 1) ? kw : (seg == 2) ? vw : ow) + (size_t)off * 4;
        if (seg <= 1) {
            const int row = off >> 8;       // 256 float4 per 1024-elem row
            const int c4 = off & 255;
            const int h = row >> 6, fr = row & 63;
            const int pr = (fr >> 1) | ((fr & 1) << 5);
            dst = wqkv + (((size_t)(seg << 10) + h * 64 + pr) << 10) + (size_t)c4 * 4;
        } else {
            dst = ((seg == 3) ? owb : wqkv + (size_t)seg * 1048576) + (size_t)off * 4;
        }
    }
    f32x4 v = *(const f32x4*)src;
    bf16x4 o;
    o[0] = (__bf16)v[0]; o[1] = (__bf16)v[1]; o[2] = (__bf16)v[2]; o[3] = (__bf16)v[3];
    *(bf16x4*)dst = o;
}

// ---------------- QKV GEMM 128x128, counted-vmcnt dbuf; fused RoPE epilogue ----------
__global__ __launch_bounds__(256) void gemm_qkv128(const __bf16* __restrict__ A,
                                                   const __bf16* __restrict__ Bt,
                                                   const float* __restrict__ tbl,
                                                   __bf16* __restrict__ Qr,
                                                   __bf16* __restrict__ Kr,
                                                   __bf16* __restrict__ Vt) {
    __shared__ __bf16 As[2][128 * 64];
    __shared__ __bf16 Bs[2][128 * 64];
    const int K = 1024, lda = 1024, ldb = 1024;
    const int tid = threadIdx.x;
    const int lane = tid & 63, w = tid >> 6;
    const int wr = w >> 1, wc = w & 1;
    const int l15 = lane & 15, lg = lane >> 4;
    const int m0 = blockIdx.y * 128, n0 = blockIdx.x * 128;
    const int crow = lane >> 3;
    const int csw = ((lane & 7) ^ crow) * 8;

    f32x4 acc[4][4];
    const f32x4 z = {0.f, 0.f, 0.f, 0.f};
#pragma unroll
    for (int i = 0; i < 4; ++i)
#pragma unroll
        for (int jx = 0; jx < 4; ++jx) acc[i][jx] = z;

    auto stage = [&](int buf, int k0) {
#pragma unroll
        for (int ch = 0; ch < 4; ++ch) {
            const int cid = w * 4 + ch;
            const int ra = cid * 8 + crow;
            gload_lds16(&A[(size_t)(m0 + ra) * lda + k0 + csw], &As[buf][cid * 512]);
            gload_lds16(&Bt[(size_t)(n0 + ra) * ldb + k0 + csw], &Bs[buf][cid * 512]);
        }
    };

    stage(0, 0);
    int cur = 0;
    for (int k0 = 0; k0 < K; k0 += 64) {
        if (k0 + 64 < K) {
            stage(cur ^ 1, k0 + 64);
            asm volatile("s_waitcnt vmcnt(8)" ::: "memory");
        } else {
            asm volatile("s_waitcnt vmcnt(0)" ::: "memory");
        }
        __builtin_amdgcn_s_barrier();
        __builtin_amdgcn_sched_barrier(0);
#pragma unroll
        for (int kc = 0; kc < 2; ++kc) {
            bf16x8 af[4], bfv[4];
#pragma unroll
            for (int i = 0; i < 4; ++i) {
                const int ra = wr * 64 + i * 16 + l15;
                const int rb = wc * 64 + i * 16 + l15;
                af[i]  = *(const bf16x8*)&As[cur][ra * 64 + ((kc * 32 + lg * 8) ^ ((ra & 7) << 3))];
                bfv[i] = *(const bf16x8*)&Bs[cur][rb * 64 + ((kc * 32 + lg * 8) ^ ((rb & 7) << 3))];
            }
#pragma unroll
            for (int sm = 0; sm < 4; ++sm)
#pragma unroll
                for (int sn = 0; sn < 4; ++sn)
                    acc[sm][sn] = __builtin_amdgcn_mfma_f32_16x16x32_bf16(af[sm], bfv[sn], acc[sm][sn], 0, 0, 0);
        }
        asm volatile("s_waitcnt lgkmcnt(0)" ::: "memory");
        __builtin_amdgcn_s_barrier();
        __builtin_amdgcn_sched_barrier(0);
        cur ^= 1;
    }
    if (n0 < 2048) {
        __bf16* dst = (n0 < 1024) ? Qr : Kr;
        const float scale = (n0 < 1024) ? QSCALE : 1.0f;
        const int h = ((n0 & 1023) + wc * 64) >> 6;
#pragma unroll
        for (int sm = 0; sm < 4; ++sm)
#pragma unroll
            for (int j = 0; j < 4; ++j) {
                const int row = m0 + wr * 64 + sm * 16 + lg * 4 + j;
                const int b = row >> 11, s = row & (NS - 1);
                const size_t base = ((size_t)(b * NH + h) * NS + s) * 64;
#pragma unroll
                for (int pp = 0; pp < 2; ++pp) {
                    const int jj = pp * 16 + l15;
                    f32x2 cssn = *(const f32x2*)&tbl[((size_t)s * 32 + jj) * 2];
                    const float e  = acc[sm][pp][j];
                    const float od = acc[sm][pp + 2][j];
                    bf16x2 ov;
                    ov[0] = (__bf16)((e * cssn[0] - od * cssn[1]) * scale);
                    ov[1] = (__bf16)((e * cssn[1] + od * cssn[0]) * scale);
                    *(bf16x2*)&dst[base + 2 * jj] = ov;
                }
            }
    } else {
#pragma unroll
        for (int sm = 0; sm < 4; ++sm)
#pragma unroll
            for (int sn = 0; sn < 4; ++sn) {
                const int col = (n0 - 2048) + wc * 64 + sn * 16 + l15;
                const int h = col >> 6, d = col & 63;
                const int row = m0 + wr * 64 + sm * 16 + lg * 4;
                const int b = row >> 11, s = row & (NS - 1);
                bf16x4 ov;
#pragma unroll
                for (int j = 0; j < 4; ++j) ov[j] = (__bf16)acc[sm][sn][j];
                *(bf16x4*)&Vt[((size_t)(b * NH + h) * 64 + d) * NS + s] = ov;
            }
    }
}

// ---------------- GEMM 128x128 with counted-vmcnt loop (output projection) ----------------
template <typename TOUT>
__global__ __launch_bounds__(256) void gemm_bt128(const __bf16* __restrict__ A,
                                                  const __bf16* __restrict__ Bt,
                                                  TOUT* __restrict__ C,
                                                  int K, int lda, int ldb, int ldc) {
    __shared__ __bf16 As[2][128 * 64];
    __shared__ __bf16 Bs[2][128 * 64];
    const int tid = threadIdx.x;
    const int lane = tid & 63, w = tid >> 6;
    const int wr = w >> 1, wc = w & 1;
    const int l15 = lane & 15, lg = lane >> 4;
    const int m0 = blockIdx.y * 128, n0 = blockIdx.x * 128;
    const int crow = lane >> 3;
    const int csw = ((lane & 7) ^ crow) * 8;

    f32x4 acc[4][4];
    const f32x4 z = {0.f, 0.f, 0.f, 0.f};
#pragma unroll
    for (int i = 0; i < 4; ++i)
#pragma unroll
        for (int jx = 0; jx < 4; ++jx) acc[i][jx] = z;

    auto stage = [&](int buf, int k0) {
#pragma unroll
        for (int ch = 0; ch < 4; ++ch) {
            const int cid = w * 4 + ch;
            const int ra = cid * 8 + crow;
            gload_lds16(&A[(size_t)(m0 + ra) * lda + k0 + csw], &As[buf][cid * 512]);
            gload_lds16(&Bt[(size_t)(n0 + ra) * ldb + k0 + csw], &Bs[buf][cid * 512]);
        }
    };

    stage(0, 0);
    int cur = 0;
    for (int k0 = 0; k0 < K; k0 += 64) {
        if (k0 + 64 < K) {
            stage(cur ^ 1, k0 + 64);
            asm volatile("s_waitcnt vmcnt(8)" ::: "memory");
        } else {
            asm volatile("s_waitcnt vmcnt(0)" ::: "memory");
        }
        __builtin_amdgcn_s_barrier();
        __builtin_amdgcn_sched_barrier(0);
#pragma unroll
        for (int kc = 0; kc < 2; ++kc) {
            bf16x8 af[4], bfv[4];
#pragma unroll
            for (int i = 0; i < 4; ++i) {
                const int ra = wr * 64 + i * 16 + l15;
                const int rb = wc * 64 + i * 16 + l15;
                af[i]  = *(const bf16x8*)&As[cur][ra * 64 + ((kc * 32 + lg * 8) ^ ((ra & 7) << 3))];
                bfv[i] = *(const bf16x8*)&Bs[cur][rb * 64 + ((kc * 32 + lg * 8) ^ ((rb & 7) << 3))];
            }
#pragma unroll
            for (int sm = 0; sm < 4; ++sm)
#pragma unroll
                for (int sn = 0; sn < 4; ++sn)
                    acc[sm][sn] = __builtin_amdgcn_mfma_f32_16x16x32_bf16(af[sm], bfv[sn], acc[sm][sn], 0, 0, 0);
        }
        asm volatile("s_waitcnt lgkmcnt(0)" ::: "memory");
        __builtin_amdgcn_s_barrier();
        __builtin_amdgcn_sched_barrier(0);
        cur ^= 1;
    }
#pragma unroll
    for (int sm = 0; sm < 4; ++sm)
#pragma unroll
        for (int sn = 0; sn < 4; ++sn)
#pragma unroll
            for (int j = 0; j < 4; ++j) {
                const int row = m0 + wr * 64 + sm * 16 + lg * 4 + j;
                const int col = n0 + wc * 64 + sn * 16 + l15;
                C[(size_t)row * ldc + col] = (TOUT)acc[sm][sn][j];
            }
}

// K staging permutation (zero-exchange PV): LDS slot rt holds K row kperm(rt).
__device__ __forceinline__ int kperm(int rt) {
    const int ct = rt >> 4, rr = rt & 15;
    return ((rr >> 2) << 3) + ((ct >> 1) << 5) + ((ct & 1) << 2) + (rr & 3);
}

// ---------------- causal flash attention v9: 1 q-tile (64 rows) per block, grid 1024 ----
// 4 waves x 1 rowset (low VGPR -> high occupancy); longest tiles dispatched first (LPT).
// Fixed-max exp2 softmax, deferred cross-lane lsum reduce.
__global__ __launch_bounds__(256) void attn9(const __bf16* __restrict__ Qr,
                                             const __bf16* __restrict__ Kr,
                                             const __bf16* __restrict__ Vt,
                                             __bf16* __restrict__ O) {
    const int lid = blockIdx.x;
    const int xcd = lid & 7;
    const int g = lid >> 3;                 // 0..127
    const int bh = xcd * 4 + (g & 3);       // 4 heads per XCD (L2 locality)
    const int ti = 31 - (g >> 2);           // 31..0  -> longest blocks dispatch first
    const int q0 = ti * 64;
    const int b = bh >> 4, h = bh & 15;
    const int tid = threadIdx.x;
    const int w = tid >> 6, lane = tid & 63;
    const int l15 = lane & 15, lg = lane >> 4;
    const __bf16* Qb = Qr + (size_t)bh * NS * 64;
    const __bf16* Kb = Kr + (size_t)bh * NS * 64;
    const __bf16* Vb = Vt + (size_t)bh * 64 * NS;

    __shared__ __bf16 Ks[2][64 * 64];
    __shared__ __bf16 Vs[2][64 * 64];

    const int rb = q0 + w * 16;

    bf16x8 qf[2];
#pragma unroll
    for (int kc = 0; kc < 2; ++kc)
        qf[kc] = *(const bf16x8*)(Qb + (size_t)(rb + l15) * 64 + kc * 32 + lg * 8);

    f32x4 oacc[4];
    const f32x4 z = {0.f, 0.f, 0.f, 0.f};
#pragma unroll
    for (int ct = 0; ct < 4; ++ct) oacc[ct] = z;
    float lsum = 0.f;

    const int crow = lane >> 3;
    const int cswz = ((lane & 7) ^ crow) * 8;

#pragma unroll
    for (int pp = 0; pp < 2; ++pp) {
        const int ch = w + pp * 4;
        const int rt = ch * 8 + crow;
        gload_lds16(Kb + (size_t)kperm(rt) * 64 + cswz, &Ks[0][ch * 512]);
        gload_lds16(Vb + (size_t)rt * NS + 0 + cswz, &Vs[0][ch * 512]);
    }
    __syncthreads();

    const int nt = ti + 1;
    for (int t = 0; t < nt; ++t) {
        const int cur = t & 1;
        const int kv0 = t << 6;
        if (t + 1 < nt) {
            const int kv1 = kv0 + 64;
#pragma unroll
            for (int pp = 0; pp < 2; ++pp) {
                const int ch = w + pp * 4;
                const int rt = ch * 8 + crow;
                gload_lds16(Kb + (size_t)(kv1 + kperm(rt)) * 64 + cswz, &Ks[cur ^ 1][ch * 512]);
                gload_lds16(Vb + (size_t)rt * NS + kv1 + cswz, &Vs[cur ^ 1][ch * 512]);
            }
        }
        f32x4 sc[4];
#pragma unroll
        for (int ct = 0; ct < 4; ++ct) sc[ct] = z;
#pragma unroll
        for (int kc = 0; kc < 2; ++kc) {
            bf16x8 kf[4];
#pragma unroll
            for (int ct = 0; ct < 4; ++ct) {
                const int rt = ct * 16 + l15;
                kf[ct] = *(const bf16x8*)&Ks[cur][rt * 64 + ((kc * 32 + lg * 8) ^ ((rt & 7) << 3))];
            }
#pragma unroll
            for (int ct = 0; ct < 4; ++ct)
                sc[ct] = __builtin_amdgcn_mfma_f32_16x16x32_bf16(kf[ct], qf[kc], sc[ct], 0, 0, 0);
        }
        const int qrow = rb + l15;
        if (t == nt - 1) {
#pragma unroll
            for (int ct = 0; ct < 4; ++ct)
#pragma unroll
                for (int j = 0; j < 4; ++j) {
                    const int kvg = kv0 + ((ct >> 1) << 5) + lg * 8 + ((ct & 1) << 2) + j;
                    if (kvg > qrow) sc[ct][j] = -1e30f;
                }
        }
        float ps = 0.f;
#pragma unroll
        for (int ct = 0; ct < 4; ++ct)
#pragma unroll
            for (int j = 0; j < 4; ++j) {
                const float e = EXP2F(sc[ct][j]);
                sc[ct][j] = e;
                ps += e;
            }
        lsum += ps;
        bf16x8 pb[2];
#pragma unroll
        for (int kc = 0; kc < 2; ++kc) {
            bf16x8 pk;
            pk[0] = (__bf16)sc[2 * kc][0];     pk[1] = (__bf16)sc[2 * kc][1];
            pk[2] = (__bf16)sc[2 * kc][2];     pk[3] = (__bf16)sc[2 * kc][3];
            pk[4] = (__bf16)sc[2 * kc + 1][0]; pk[5] = (__bf16)sc[2 * kc + 1][1];
            pk[6] = (__bf16)sc[2 * kc + 1][2]; pk[7] = (__bf16)sc[2 * kc + 1][3];
            pb[kc] = pk;
        }
#pragma unroll
        for (int kc = 0; kc < 2; ++kc) {
            bf16x8 vf[4];
#pragma unroll
            for (int ct = 0; ct < 4; ++ct) {
                const int rt = ct * 16 + l15;
                vf[ct] = *(const bf16x8*)&Vs[cur][rt * 64 + ((kc * 32 + lg * 8) ^ ((rt & 7) << 3))];
            }
#pragma unroll
            for (int ct = 0; ct < 4; ++ct)
                oacc[ct] = __builtin_amdgcn_mfma_f32_16x16x32_bf16(vf[ct], pb[kc], oacc[ct], 0, 0, 0);
        }
        __syncthreads();
    }
    float tot = lsum;
    tot += __shfl_xor(tot, 16, 64);
    tot += __shfl_xor(tot, 32, 64);
    const float rl = 1.0f / tot;
    const size_t rowoff = (size_t)(b * NS + rb + l15) * NDM + h * 64 + lg * 4;
#pragma unroll
    for (int ct = 0; ct < 4; ++ct) {
        bf16x4 ov;
#pragma unroll
        for (int j = 0; j < 4; ++j) ov[j] = (__bf16)(oacc[ct][j] * rl);
        *(bf16x4*)&O[rowoff + ct * 16] = ov;
    }
}

// ---------------- launch ----------------
extern "C" void kernel_launch(void* const* d_in, const int* in_sizes, int n_in,
                              void* d_out, int out_size, void* d_ws, size_t ws_size,
                              hipStream_t stream) {
    const float* x  = (const float*)d_in[0];
    const float* Qw = (const float*)d_in[1];
    const float* Kw = (const float*)d_in[2];
    const float* Vw = (const float*)d_in[3];
    const float* Ow = (const float*)d_in[4];
    const int*   tp = (const int*)d_in[5];
    float* out = (float*)d_out;

    char* ws = (char*)d_ws;
    size_t off = 0;
    auto alloc = [&](size_t bytes) -> void* {
        void* p = ws + off;
        off += (bytes + 255) & ~(size_t)255;
        return p;
    };
    __bf16* xb   = (__bf16*)alloc((size_t)4096 * 1024 * 2);
    __bf16* wqkv = (__bf16*)alloc((size_t)3072 * 1024 * 2);
    __bf16* owb  = (__bf16*)alloc((size_t)1024 * 1024 * 2);
    __bf16* qr   = (__bf16*)alloc((size_t)32 * 2048 * 64 * 2);
    __bf16* kr   = (__bf16*)alloc((size_t)32 * 2048 * 64 * 2);
    __bf16* vt   = (__bf16*)alloc((size_t)32 * 64 * 2048 * 2);
    __bf16* ob   = (__bf16*)alloc((size_t)4096 * 1024 * 2);
    float*  tbl  = (float*)alloc((size_t)NS * 32 * 2 * 4);

    cvt_all<<<8448, 256, 0, stream>>>(x, Qw, Kw, Vw, Ow, tp, xb, wqkv, owb, tbl);

    gemm_qkv128<<<dim3(3072 / 128, 4096 / 128), 256, 0, stream>>>(xb, wqkv, tbl, qr, kr, vt);
    attn9<<<dim3(1024), 256, 0, stream>>>(qr, kr, vt, ob);
    gemm_bt128<float><<<dim3(1024 / 128, 4096 / 128), 256, 0, stream>>>(
        ob, owb, out, 1024, 1024, 1024, 1024);
}